// Round 2
// baseline (158.969 us; speedup 1.0000x reference)
//
#include <hip/hip_runtime.h>

// Problem constants (fixed by reference)
constexpr int Bn = 4, Cn = 64, Hn = 192, Wn = 640, HW = Hn * Wn;
constexpr int TW = 64, TH = 16;           // output tile per block
constexpr int SH = TH + 4, SW = TW + 4;   // 20 x 68 tile+halo
constexpr int NS = SH * SW;               // 1360
constexpr int NT = 256;                   // 16 thr-x (4 px each) x 16 thr-y
constexpr int CH = 2;                     // channels staged per chunk
constexpr int NCHUNK = Cn / CH;           // 32
constexpr int E = (NS + NT - 1) / NT;     // 6 staging elems/thread (last partial)

__global__ __launch_bounds__(NT, 3) void guide_triplet_kernel(
    const float* __restrict__ pred,
    const int*   __restrict__ target,
    float* __restrict__ out)
{
    __shared__ alignas(16) float slice[2][CH][NS];  // double-buffered channel slices
    __shared__ float invnS[NS];
    __shared__ int   lblS[NS];

    const int x0 = blockIdx.x * TW;
    const int y0 = blockIdx.y * TH;
    const int b  = blockIdx.z;

    const int tid = threadIdx.x;
    const int tx  = tid & 15;    // 0..15 -> output cols x0 + 4*tx .. +3
    const int ty  = tid >> 4;    // 0..15 -> output row  y0 + ty

    // ---- staging geometry (loop-invariant) ----
    int  off[E];
    bool ok[E];
    #pragma unroll
    for (int k = 0; k < E; ++k) {
        const int e = tid + NT * k;
        const int r = e / SW, c = e % SW;
        const int gy = y0 + r - 2, gx = x0 + c - 2;
        ok[k]  = (e < NS) && (gy >= 0) && (gy < Hn) && (gx >= 0) && (gx < Wn);
        off[k] = gy * Wn + gx;
    }

    // ---- labels once ----
    {
        const int* tb = target + b * HW;
        #pragma unroll
        for (int k = 0; k < E; ++k) {
            const int e = tid + NT * k;
            if (e < NS) lblS[e] = ok[k] ? tb[off[k]] : -1;
        }
    }

    float ss[E];
    #pragma unroll
    for (int k = 0; k < E; ++k) ss[k] = 0.0f;

    float acc[4][25];
    #pragma unroll
    for (int q = 0; q < 4; ++q)
        #pragma unroll
        for (int i = 0; i < 25; ++i) acc[q][i] = 0.0f;

    const float* predb = pred + (size_t)b * Cn * HW;

    // ---- prologue: load chunk 0 into registers ----
    float ld[CH][E];
    #pragma unroll
    for (int cc = 0; cc < CH; ++cc)
        #pragma unroll
        for (int k = 0; k < E; ++k)
            ld[cc][k] = ok[k] ? predb[cc * HW + off[k]] : 0.0f;

    // ---- main loop:  W(k) | sync | L(k+1) | C(k)  (loads hide under C) ----
    for (int chunk = 0; chunk < NCHUNK; ++chunk) {
        float* sb = &slice[chunk & 1][0][0];

        // W(chunk): registers -> LDS, fold into sumsq
        #pragma unroll
        for (int cc = 0; cc < CH; ++cc)
            #pragma unroll
            for (int k = 0; k < E; ++k) {
                const int e = tid + NT * k;
                if (e < NS) {
                    const float v = ld[cc][k];
                    sb[cc * NS + e] = v;
                    ss[k] = fmaf(v, v, ss[k]);
                }
            }
        __syncthreads();

        // L(chunk+1): issue next chunk's global loads (latency hidden by C below)
        if (chunk + 1 < NCHUNK) {
            const float* pc = predb + (size_t)(chunk + 1) * CH * HW;
            #pragma unroll
            for (int cc = 0; cc < CH; ++cc)
                #pragma unroll
                for (int k = 0; k < E; ++k)
                    ld[cc][k] = ok[k] ? pc[cc * HW + off[k]] : 0.0f;
        }

        // C(chunk): 4 outputs/thread, aligned b128 row reads
        #pragma unroll
        for (int cc = 0; cc < CH; ++cc) {
            const float* sc = sb + cc * NS + ty * SW + 4 * tx;
            // row r=2 first (holds the 4 center values, cols 4tx+2..5 -> elems 2..5)
            const float4 m0 = *(const float4*)(sc + 2 * SW);
            const float4 m1 = *(const float4*)(sc + 2 * SW + 4);
            const float rv[8] = {m0.x, m0.y, m0.z, m0.w, m1.x, m1.y, m1.z, m1.w};
            const float c0 = rv[2], c1 = rv[3], c2 = rv[4], c3 = rv[5];
            #pragma unroll
            for (int dj = 0; dj < 5; ++dj) {
                acc[0][10 + dj] = fmaf(c0, rv[0 + dj], acc[0][10 + dj]);
                acc[1][10 + dj] = fmaf(c1, rv[1 + dj], acc[1][10 + dj]);
                acc[2][10 + dj] = fmaf(c2, rv[2 + dj], acc[2][10 + dj]);
                acc[3][10 + dj] = fmaf(c3, rv[3 + dj], acc[3][10 + dj]);
            }
            #pragma unroll
            for (int rr = 0; rr < 4; ++rr) {
                const int r = (rr < 2) ? rr : rr + 1;   // 0,1,3,4 (const-folded)
                const float4 a0 = *(const float4*)(sc + r * SW);
                const float4 a1 = *(const float4*)(sc + r * SW + 4);
                const float w[8] = {a0.x, a0.y, a0.z, a0.w, a1.x, a1.y, a1.z, a1.w};
                #pragma unroll
                for (int dj = 0; dj < 5; ++dj) {
                    acc[0][r * 5 + dj] = fmaf(c0, w[0 + dj], acc[0][r * 5 + dj]);
                    acc[1][r * 5 + dj] = fmaf(c1, w[1 + dj], acc[1][r * 5 + dj]);
                    acc[2][r * 5 + dj] = fmaf(c2, w[2 + dj], acc[2][r * 5 + dj]);
                    acc[3][r * 5 + dj] = fmaf(c3, w[3 + dj], acc[3][r * 5 + dj]);
                }
            }
        }
    }

    // ---- inverse norms ----
    #pragma unroll
    for (int k = 0; k < E; ++k) {
        const int e = tid + NT * k;
        if (e < NS) invnS[e] = 1.0f / fmaxf(sqrtf(ss[k]), 1e-12f);
    }
    __syncthreads();

    // ---- epilogue: triplet margin per output pixel ----
    const int ebase = ty * SW + 4 * tx;
    float icn[4]; int lc[4];
    #pragma unroll
    for (int q = 0; q < 4; ++q) {
        icn[q] = invnS[ebase + 2 * SW + 2 + q];
        lc[q]  = lblS [ebase + 2 * SW + 2 + q];
    }
    float pn[4] = {0, 0, 0, 0}, nn[4] = {0, 0, 0, 0};
    float ps[4] = {0, 0, 0, 0}, ns[4] = {0, 0, 0, 0};
    #pragma unroll
    for (int r = 0; r < 5; ++r) {
        #pragma unroll
        for (int m = 0; m < 8; ++m) {
            const float in_ = invnS[ebase + r * SW + m];
            const int   lb  = lblS [ebase + r * SW + m];
            #pragma unroll
            for (int q = 0; q < 4; ++q) {
                const int dj = m - q;
                if (dj >= 0 && dj < 5) {
                    const float sim = acc[q][r * 5 + dj] * icn[q] * in_;
                    const float aff = sqrtf(fmaxf(1e-9f, 2.0f - 2.0f * sim));
                    const float mf  = (lb == lc[q]) ? 1.0f : 0.0f;
                    pn[q] += mf;
                    nn[q] += 1.0f - mf;
                    ps[q] = fmaf(mf, aff, ps[q]);
                    ns[q] = fmaf(1.0f - mf, aff, ns[q]);
                }
            }
        }
    }
    float res[4];
    #pragma unroll
    for (int q = 0; q < 4; ++q) {
        const bool  bd = (pn[q] >= 4.0f) && (nn[q] >= 4.0f);
        const float tr = fmaxf(0.0f,
            ps[q] / pn[q] - ns[q] / fmaxf(nn[q], 1e-12f) + 0.3f);
        res[q] = bd ? tr : 0.0f;
    }
    float4 o = make_float4(res[0], res[1], res[2], res[3]);
    *(float4*)&out[((size_t)b * Hn + (y0 + ty)) * Wn + x0 + 4 * tx] = o;
}

extern "C" void kernel_launch(void* const* d_in, const int* in_sizes, int n_in,
                              void* d_out, int out_size, void* d_ws, size_t ws_size,
                              hipStream_t stream) {
    const float* pred   = (const float*)d_in[0];
    const int*   target = (const int*)d_in[1];
    float*       out    = (float*)d_out;
    dim3 grid(Wn / TW, Hn / TH, Bn);   // 10 x 12 x 4 = 480 blocks
    guide_triplet_kernel<<<grid, NT, 0, stream>>>(pred, target, out);
}

// Round 3
// 86.897 us; speedup vs baseline: 1.8294x; 1.8294x over previous
//
#include <hip/hip_runtime.h>

// Problem constants (fixed by reference)
constexpr int Bn = 4, Cn = 64, Hn = 192, Wn = 640, HW = Hn * Wn;
constexpr int TH = 8, TW = 64;            // output tile per block
constexpr int SH = TH + 4, SW = TW + 4;   // 12 x 68 tile+halo
constexpr int NS = SH * SW;               // 816
constexpr int NT = 512;                   // 1 px/thread
constexpr int CH = 4;                     // channels staged per chunk
constexpr int NCHUNK = Cn / CH;           // 16

__global__ __launch_bounds__(NT, 4) void guide_triplet_kernel(
    const float* __restrict__ pred,
    const int*   __restrict__ target,
    float* __restrict__ out)
{
    __shared__ float slice[2][CH][NS];   // double-buffered channel slices (26 KB)
    __shared__ float invnS[NS];
    __shared__ int   lblS[NS];

    const int x0 = blockIdx.x * TW;
    const int y0 = blockIdx.y * TH;
    const int b  = blockIdx.z;

    const int tid = threadIdx.x;
    const int tx  = tid & (TW - 1);   // 0..63
    const int ty  = tid >> 6;         // 0..7

    // staging geometry (2 elements/thread, 2nd partial)
    const int e0 = tid;
    const int e1 = tid + NT;
    const bool has1 = (e1 < NS);      // tid < 304
    const int r0 = e0 / SW, c0 = e0 % SW;
    const int r1 = e1 / SW, c1 = e1 % SW;
    const int gy0 = y0 + r0 - 2, gx0 = x0 + c0 - 2;
    const int gy1 = y0 + r1 - 2, gx1 = x0 + c1 - 2;
    const bool ok0 = (gy0 >= 0) && (gy0 < Hn) && (gx0 >= 0) && (gx0 < Wn);
    const bool ok1 = has1 && (gy1 >= 0) && (gy1 < Hn) && (gx1 >= 0) && (gx1 < Wn);
    const int off0 = gy0 * Wn + gx0;
    const int off1 = gy1 * Wn + gx1;

    // labels once (pad = -1)
    {
        const int* tb = target + b * HW;
        lblS[e0] = ok0 ? tb[off0] : -1;
        if (has1) lblS[e1] = ok1 ? tb[off1] : -1;
    }

    float ss0 = 0.0f, ss1 = 0.0f;
    float acc[25];
    #pragma unroll
    for (int i = 0; i < 25; ++i) acc[i] = 0.0f;

    const float* predb = pred + (size_t)b * Cn * HW;

    // prologue: chunk 0 into registers
    float ld0[CH], ld1[CH];
    #pragma unroll
    for (int cc = 0; cc < CH; ++cc) {
        ld0[cc] = ok0 ? predb[cc * HW + off0] : 0.0f;
        ld1[cc] = ok1 ? predb[cc * HW + off1] : 0.0f;
    }

    // main loop:  W(k) | sync | issue L(k+1) | C(k)
    for (int chunk = 0; chunk < NCHUNK; ++chunk) {
        float (*sb)[NS] = slice[chunk & 1];

        // W(k): registers -> LDS, fold sumsq
        #pragma unroll
        for (int cc = 0; cc < CH; ++cc) {
            sb[cc][e0] = ld0[cc];
            ss0 = fmaf(ld0[cc], ld0[cc], ss0);
            if (has1) {
                sb[cc][e1] = ld1[cc];
                ss1 = fmaf(ld1[cc], ld1[cc], ss1);
            }
        }
        __syncthreads();

        // L(k+1): issue next chunk's loads; latency hidden under C(k)
        if (chunk + 1 < NCHUNK) {
            const float* pc = predb + (size_t)(chunk + 1) * CH * HW;
            #pragma unroll
            for (int cc = 0; cc < CH; ++cc) {
                ld0[cc] = ok0 ? pc[cc * HW + off0] : 0.0f;
                ld1[cc] = ok1 ? pc[cc * HW + off1] : 0.0f;
            }
        }

        // C(k): 25 scalar LDS reads + 25 FMA per channel (conflict-free)
        #pragma unroll
        for (int cc = 0; cc < CH; ++cc) {
            const float* sc = &sb[cc][ty * SW + tx];
            const float f = sc[2 * SW + 2];
            #pragma unroll
            for (int di = 0; di < 5; ++di) {
                #pragma unroll
                for (int dj = 0; dj < 5; ++dj) {
                    acc[di * 5 + dj] = fmaf(f, sc[di * SW + dj], acc[di * 5 + dj]);
                }
            }
        }
        // no tail barrier: double buffer + next iteration's barrier protect reuse
    }

    // inverse norms
    invnS[e0] = 1.0f / fmaxf(sqrtf(ss0), 1e-12f);
    if (has1) invnS[e1] = 1.0f / fmaxf(sqrtf(ss1), 1e-12f);
    __syncthreads();

    // epilogue: triplet margin (all indices compile-time static)
    const int cbase = (ty + 2) * SW + (tx + 2);
    const float ic = invnS[cbase];
    const int   lc = lblS[cbase];

    float pos_num = 0.0f, neg_num = 0.0f, pos_sum = 0.0f, neg_sum = 0.0f;
    #pragma unroll
    for (int di = 0; di < 5; ++di) {
        #pragma unroll
        for (int dj = 0; dj < 5; ++dj) {
            const int e = (ty + di) * SW + (tx + dj);
            const float sim = acc[di * 5 + dj] * ic * invnS[e];
            const float aff = sqrtf(fmaxf(1e-9f, 2.0f - 2.0f * sim));
            const float mf  = (lblS[e] == lc) ? 1.0f : 0.0f;
            pos_num += mf;
            neg_num += 1.0f - mf;
            pos_sum = fmaf(mf, aff, pos_sum);
            neg_sum = fmaf(1.0f - mf, aff, neg_sum);
        }
    }
    const bool boundary = (pos_num >= 4.0f) && (neg_num >= 4.0f);
    const float tri = fmaxf(0.0f,
        pos_sum / pos_num - neg_sum / fmaxf(neg_num, 1e-12f) + 0.3f);
    out[((size_t)b * Hn + (y0 + ty)) * Wn + (x0 + tx)] = boundary ? tri : 0.0f;
}

extern "C" void kernel_launch(void* const* d_in, const int* in_sizes, int n_in,
                              void* d_out, int out_size, void* d_ws, size_t ws_size,
                              hipStream_t stream) {
    const float* pred   = (const float*)d_in[0];
    const int*   target = (const int*)d_in[1];
    float*       out    = (float*)d_out;
    dim3 grid(Wn / TW, Hn / TH, Bn);   // 10 x 24 x 4 = 960 blocks
    guide_triplet_kernel<<<grid, NT, 0, stream>>>(pred, target, out);
}